// Round 4
// baseline (344.340 us; speedup 1.0000x reference)
//
#include <hip/hip_runtime.h>

#define DD 256        // D
#define SS 256        // S
#define BB 64         // B
#define NEDGE 500000  // E
#define MM 2048       // M
#define NEG_INF -10000000000.0f
#define ROWF4 512     // float4 stride between consecutive (b,s) type rows in token_reprs
#define NROWS (BB * SS)  // 16384

// edge kernel geometry: XCD-affine dynamic work claiming
#define EPB0 256
#define NCHUNK ((NEDGE + EPB0 - 1) / EPB0)   // 1954
#define NBLK_E (4 * NCHUNK)                  // one block per (pair, chunk) item
#define PPAD 500224                          // NEDGE padded to 256-multiple

// workspace byte offsets (ws is 512 MB per harness poison fills)
#define OFF_VC     0
#define OFF_CNT    2048                      // 4 ints, work-claim counters
#define OFF_MSORT  4096
#define OFF_BSTART (4096 + MM * 4)
#define OFF_ASLAB  (1 << 16)
#define OFF_MROWS  ((1 << 16) + (16 << 20))
#define OFF_PART   ((1 << 16) + (17 << 20))  // 4 x PPAD floats ~ 8 MB

typedef float vf4 __attribute__((ext_vector_type(4)));  // native vector for nontemporal builtins

__device__ __forceinline__ float bflo(unsigned u) { return __uint_as_float(u << 16); }
__device__ __forceinline__ float bfhi(unsigned u) { return __uint_as_float(u & 0xFFFF0000u); }
__device__ __forceinline__ unsigned short bf_rne(float f) {
    unsigned u = __float_as_uint(f);
    return (unsigned short)((u + 0x7FFFu + ((u >> 16) & 1u)) >> 16);
}
__device__ __forceinline__ unsigned pack2_rne(float a, float b) {
    return (unsigned)bf_rne(a) | ((unsigned)bf_rne(b) << 16);
}

// block 0: vc[d] = sum_j w1[d,j]*w2[j], vc[256] = b1.w2+b2  (wave-per-row, coalesced)
// block 1: counting-sort m by batch pointer; zero the claim counters
__global__ void setup_k(const float* __restrict__ w1, const float* __restrict__ b1,
                        const float* __restrict__ w2, const float* __restrict__ b2,
                        const int* __restrict__ bp,
                        float* __restrict__ vc, int* __restrict__ msorted,
                        int* __restrict__ bstart, int* __restrict__ cnt) {
    const int t = threadIdx.x;
    if (blockIdx.x == 0) {
        __shared__ float sw2[DD / 2];
        if (t < DD / 2) sw2[t] = w2[t];
        __syncthreads();
        const int lane = t & 63, w = t >> 6;
        for (int r = w; r < DD; r += 4) {
            float x = w1[r * (DD / 2) + lane] * sw2[lane]
                    + w1[r * (DD / 2) + 64 + lane] * sw2[64 + lane];
            x += __shfl_down(x, 32);
            x += __shfl_down(x, 16);
            x += __shfl_down(x, 8);
            x += __shfl_down(x, 4);
            x += __shfl_down(x, 2);
            x += __shfl_down(x, 1);
            if (lane == 0) vc[r] = x;
        }
        if (w == 0) {
            float x = b1[lane] * sw2[lane] + b1[64 + lane] * sw2[64 + lane];
            x += __shfl_down(x, 32);
            x += __shfl_down(x, 16);
            x += __shfl_down(x, 8);
            x += __shfl_down(x, 4);
            x += __shfl_down(x, 2);
            x += __shfl_down(x, 1);
            if (lane == 0) vc[DD] = x + b2[0];
        }
    } else {
        __shared__ int hist[BB];
        __shared__ int offs[BB + 1];
        if (t < 4) cnt[t] = 0;               // reset work-claim counters
        if (t < BB) hist[t] = 0;
        __syncthreads();
        for (int m = t; m < MM; m += 256) atomicAdd(&hist[bp[m]], 1);
        __syncthreads();
        if (t == 0) {
            int acc = 0;
            for (int i = 0; i < BB; ++i) { offs[i] = acc; acc += hist[i]; }
            offs[BB] = acc;
        }
        __syncthreads();
        if (t < BB + 1) bstart[t] = offs[t];
        __syncthreads();
        for (int m = t; m < MM; m += 256) {
            int pos = atomicAdd(&offs[bp[m]], 1);
            msorted[pos] = m;
        }
    }
}

// Compact strided fp32 rows into dense bf16 tables:
//  blocks [0, NROWS/4): type rows -> aslab (slice-major, serves BOTH the edge
//                       gathers and lm_gemm's B staging)
//  blocks [NROWS/4, +MM/4): mask rows via lm_indices -> mrows (row-major)
__global__ __launch_bounds__(256) void compact(
        const float* __restrict__ tok, const int* __restrict__ lmi,
        unsigned* __restrict__ aslab, unsigned* __restrict__ mrows) {
    const int lane = threadIdx.x & 63;
    const int w    = threadIdx.x >> 6;
    if (blockIdx.x < NROWS / 4) {
        const int row = blockIdx.x * 4 + w;
        const float4 a = ((const float4*)tok)[(size_t)row * ROWF4 + lane];
        unsigned p0 = pack2_rne(a.x, a.y), p1 = pack2_rne(a.z, a.w);
        const int k = lane >> 3, sub = lane & 7;
        const size_t si = (size_t)(k * NROWS + row) * 16 + sub * 2;
        aslab[si] = p0; aslab[si + 1] = p1;
    } else {
        const int m = (blockIdx.x - NROWS / 4) * 4 + w;
        const float4 a = ((const float4*)(tok + (size_t)lmi[m] * DD))[lane];
        mrows[(size_t)m * 128 + lane * 2]     = pack2_rne(a.x, a.y);
        mrows[(size_t)m * 128 + lane * 2 + 1] = pack2_rne(a.z, a.w);
    }
}

// XCD-AFFINE edge kernel: each block reads its REAL XCD id (HW_REG_XCC_ID,
// gfx950-verified) and claims a (slice-pair, chunk) item from global counters,
// preferring pair = xcc/2 so each XCD's L2 holds one 2MB slice-pair for the
// whole kernel. Cross-pair stealing keeps it correct regardless of how the
// dispatcher assigns blocks to XCDs. Partials go to pp[pair][e] (nontemporal,
// no table eviction); combine() reduces.
__global__ __launch_bounds__(256) void edge_part(
        const unsigned* __restrict__ aslab,
        const int* __restrict__ edges, const float* __restrict__ vc,
        float* __restrict__ pp, int* __restrict__ cnt) {
    __shared__ int sclaim;
    const int t = threadIdx.x;
    if (t == 0) {
        unsigned xcc;
        asm volatile("s_getreg_b32 %0, hwreg(HW_REG_XCC_ID)" : "=s"(xcc));
        const int p0 = (int)(xcc >> 1) & 3;
        int got = -1;
        #pragma unroll 1
        for (int jj = 0; jj < 4; ++jj) {
            const int p = (p0 + jj) & 3;
            const int pos = atomicAdd(&cnt[p], 1);
            if (pos < NCHUNK) { got = p * NCHUNK + pos; break; }
        }
        sclaim = got;
    }
    __syncthreads();
    const int claim = sclaim;
    if (claim < 0) return;                    // all items already claimed
    const int p = claim / NCHUNK;
    const int chunk = claim - p * NCHUNK;
    const int e0 = chunk * EPB0;
    const int k0 = p * 2;

    const int lane = t & 63, w = t >> 6;
    const int sub = lane & 7, j = lane >> 3;
    __shared__ int sIdx[2][EPB0];
    __shared__ float accs[EPB0];
    const int e = e0 + t;
    const bool val = e < NEDGE;
    sIdx[0][t] = val ? __builtin_nontemporal_load(edges + e) : 0;
    sIdx[1][t] = val ? __builtin_nontemporal_load(edges + NEDGE + e) : 0;

    // per-lane v for the 2 owned slices: dims k*32 + sub*4 .. +4
    const float4 v0 = ((const float4*)vc)[k0 * 8 + sub];
    const float4 v1 = ((const float4*)vc)[(k0 + 1) * 8 + sub];
    __syncthreads();

    float acc[8];
    #pragma unroll
    for (int i = 0; i < 8; ++i) acc[i] = 0.f;
    const int slotbase = w * 64 + j;  // + i*8

    // hoist row byte-offsets out of the k loop
    int offS[8], offG[8];
    #pragma unroll
    for (int i = 0; i < 8; ++i) {
        const int slot = slotbase + i * 8;
        offS[i] = sIdx[0][slot] * 16;
        offG[i] = sIdx[1][slot] * 16;
    }

    #pragma unroll 1
    for (int kk = 0; kk < 2; ++kk) {
        const int k = k0 + kk;
        const unsigned* base = aslab + (size_t)k * (NROWS * 16) + sub * 2;
        const float4 v = kk ? v1 : v0;
        #pragma unroll
        for (int i = 0; i < 8; ++i) {
            const uint2 pu = *(const uint2*)(base + offS[i]);
            const uint2 qu = *(const uint2*)(base + offG[i]);
            acc[i] += (bflo(pu.x) * bflo(qu.x)) * v.x
                    + (bfhi(pu.x) * bfhi(qu.x)) * v.y
                    + (bflo(pu.y) * bflo(qu.y)) * v.z
                    + (bfhi(pu.y) * bfhi(qu.y)) * v.w;
        }
    }
    #pragma unroll
    for (int i = 0; i < 8; ++i) {
        float x = acc[i];
        x += __shfl_down(x, 4, 8);
        x += __shfl_down(x, 2, 8);
        x += __shfl_down(x, 1, 8);
        if (sub == 0) accs[slotbase + i * 8] = x;
    }
    __syncthreads();
    if (val) __builtin_nontemporal_store(accs[t], pp + (size_t)p * PPAD + e);
}

// out[e] = vc[DD] + sum_p pp[p][e], vectorized float4
__global__ __launch_bounds__(256) void combine(
        const float* __restrict__ pp, const float* __restrict__ vc,
        float* __restrict__ out) {
    const int i = blockIdx.x * 256 + threadIdx.x;
    if (i >= NEDGE / 4) return;
    const float c = vc[DD];
    vf4 a = ((const vf4*)pp)[i];
    vf4 b = ((const vf4*)(pp + PPAD))[i];
    vf4 d = ((const vf4*)(pp + 2 * (size_t)PPAD))[i];
    vf4 e = ((const vf4*)(pp + 3 * (size_t)PPAD))[i];
    vf4 r = a + b + d + e + c;
    __builtin_nontemporal_store(r, (vf4*)out + i);
}

// Per-batch grouped lm GEMM with masked-column skip; A staged from mrows,
// B staged directly from aslab's slice-major layout (p2 table eliminated).
__global__ __launch_bounds__(256) void lm_gemm(
        const unsigned* __restrict__ aslab,
        const unsigned* __restrict__ mrows,
        const int* __restrict__ msorted,
        const int* __restrict__ bstart,
        const int* __restrict__ tpm,
        float* __restrict__ out) {
    const int b  = blockIdx.x;
    const int st = blockIdx.y;   // 64-wide s tile
    const int ch = blockIdx.z;   // mask chunk
    const int s0 = bstart[b], s1 = bstart[b + 1];
    const int base = s0 + ch * 32;
    if (base >= s1) return;
    const int nm = min(32, s1 - base);
    const int t = threadIdx.x;

    __shared__ unsigned lmaskU[32 * 132];
    __shared__ unsigned srowU[32 * 132];
    __shared__ int mids[32];
    __shared__ int sact[64];
    __shared__ int snact;

    if (t < 32) mids[t] = msorted[base + min(t, nm - 1)];
    if (t >= 64 && t < 128) {  // wave 1: ballot-compact active columns
        int lt = t - 64;
        bool act = tpm[b * SS + st * 64 + lt] != 0;
        unsigned long long mk = __ballot(act);
        if (act) sact[__popcll(mk & ((1ull << lt) - 1))] = lt;
        if (lt == 0) snact = (int)__popcll(mk);
    }
    __syncthreads();

    for (int f = t; f < nm * 32; f += 256) {
        int r = f >> 5, q = f & 31;
        *(uint4*)&lmaskU[r * 132 + q * 4] = ((const uint4*)mrows)[(size_t)mids[r] * 32 + q];
    }
    for (int f = t; f < nm * 64; f += 256) {
        int i = f >> 6, c = f & 63;
        if (!tpm[b * SS + st * 64 + c])
            out[(size_t)mids[i] * SS + st * 64 + c] = NEG_INF;
    }
    __syncthreads();

    const int nact = snact;
    const int i2 = t & 15, sg = t >> 4;

    for (int g = 0; g * 32 < nact; ++g) {
        if (g) __syncthreads();
        const int nv = min(32, nact - g * 32);
        for (int f = t; f < nv * 32; f += 256) {
            int r = f >> 5, q = f & 31;
            size_t row = (size_t)b * SS + st * 64 + sact[g * 32 + r];
            *(uint4*)&srowU[r * 132 + q * 4] =
                ((const uint4*)aslab)[((size_t)(q >> 2) * NROWS + row) * 4 + (q & 3)];
        }
        __syncthreads();

        float a00 = 0.f, a01 = 0.f, a10 = 0.f, a11 = 0.f;
        #pragma unroll 4
        for (int stp = 0; stp < 32; ++stp) {
            const uint4 A0 = *(const uint4*)&lmaskU[i2 * 132 + stp * 4];
            const uint4 A1 = *(const uint4*)&lmaskU[(i2 + 16) * 132 + stp * 4];
            const uint4 B0 = *(const uint4*)&srowU[sg * 132 + stp * 4];
            const uint4 B1 = *(const uint4*)&srowU[(sg + 16) * 132 + stp * 4];
            float a0[8], a1[8], b0[8], b1[8];
            a0[0] = bflo(A0.x); a0[1] = bfhi(A0.x); a0[2] = bflo(A0.y); a0[3] = bfhi(A0.y);
            a0[4] = bflo(A0.z); a0[5] = bfhi(A0.z); a0[6] = bflo(A0.w); a0[7] = bfhi(A0.w);
            a1[0] = bflo(A1.x); a1[1] = bfhi(A1.x); a1[2] = bflo(A1.y); a1[3] = bfhi(A1.y);
            a1[4] = bflo(A1.z); a1[5] = bfhi(A1.z); a1[6] = bflo(A1.w); a1[7] = bfhi(A1.w);
            b0[0] = bflo(B0.x); b0[1] = bfhi(B0.x); b0[2] = bflo(B0.y); b0[3] = bfhi(B0.y);
            b0[4] = bflo(B0.z); b0[5] = bfhi(B0.z); b0[6] = bflo(B0.w); b0[7] = bfhi(B0.w);
            b1[0] = bflo(B1.x); b1[1] = bfhi(B1.x); b1[2] = bflo(B1.y); b1[3] = bfhi(B1.y);
            b1[4] = bflo(B1.z); b1[5] = bfhi(B1.z); b1[6] = bflo(B1.w); b1[7] = bfhi(B1.w);
            #pragma unroll
            for (int jj = 0; jj < 8; ++jj) {
                a00 = fmaf(a0[jj], b0[jj], a00);
                a01 = fmaf(a0[jj], b1[jj], a01);
                a10 = fmaf(a1[jj], b0[jj], a10);
                a11 = fmaf(a1[jj], b1[jj], a11);
            }
        }

        const int iA = g * 32 + sg, iB = iA + 16;
        if (i2 < nm) {
            size_t ob = (size_t)mids[i2] * SS + st * 64;
            if (iA < nact) out[ob + sact[iA]] = a00;
            if (iB < nact) out[ob + sact[iB]] = a01;
        }
        if (i2 + 16 < nm) {
            size_t ob = (size_t)mids[i2 + 16] * SS + st * 64;
            if (iA < nact) out[ob + sact[iA]] = a10;
            if (iB < nact) out[ob + sact[iB]] = a11;
        }
    }
}

extern "C" void kernel_launch(void* const* d_in, const int* in_sizes, int n_in,
                              void* d_out, int out_size, void* d_ws, size_t ws_size,
                              hipStream_t stream) {
    const float* tok = (const float*)d_in[0];
    const float* w1  = (const float*)d_in[1];
    const float* b1  = (const float*)d_in[2];
    const float* w2  = (const float*)d_in[3];
    const float* b2  = (const float*)d_in[4];
    const int* edges = (const int*)d_in[5];
    const int* lmi   = (const int*)d_in[6];
    const int* bp    = (const int*)d_in[7];
    const int* tpm   = (const int*)d_in[8];

    float* out_lemmas = (float*)d_out;
    float* out_lm     = (float*)d_out + NEDGE;

    char* ws = (char*)d_ws;
    float* vc        = (float*)(ws + OFF_VC);
    int* cnt         = (int*)(ws + OFF_CNT);
    int* msorted     = (int*)(ws + OFF_MSORT);
    int* bstart      = (int*)(ws + OFF_BSTART);
    unsigned* aslab  = (unsigned*)(ws + OFF_ASLAB);
    unsigned* mrows  = (unsigned*)(ws + OFF_MROWS);
    float* pp        = (float*)(ws + OFF_PART);

    setup_k<<<2, 256, 0, stream>>>(w1, b1, w2, b2, bp, vc, msorted, bstart, cnt);
    compact<<<NROWS / 4 + MM / 4, 256, 0, stream>>>(tok, lmi, aslab, mrows);
    edge_part<<<NBLK_E, 256, 0, stream>>>(aslab, edges, vc, pp, cnt);
    combine<<<(NEDGE / 4 + 255) / 256, 256, 0, stream>>>(pp, vc, out_lemmas);
    lm_gemm<<<dim3(BB, 4, 8), 256, 0, stream>>>(aslab, mrows, msorted, bstart, tpm, out_lm);
}

// Round 5
// 261.433 us; speedup vs baseline: 1.3171x; 1.3171x over previous
//
#include <hip/hip_runtime.h>

#define DD 256        // D
#define SS 256        // S
#define BB 64         // B
#define NEDGE 500000  // E
#define MM 2048       // M
#define NEG_INF -10000000000.0f
#define ROWF4 512     // float4 stride between consecutive (b,s) type rows in token_reprs
#define NROWS (BB * SS)  // 16384

// workspace byte offsets (ws is 512 MB per harness poison fills)
#define OFF_VC     0
#define OFF_MSORT  4096
#define OFF_BSTART (4096 + MM * 4)
#define OFF_FSLAB  (1 << 16)                  // fp8 table, 16384 x 256 B = 4 MB
#define OFF_P2     ((1 << 16) + (4 << 20))    // bf16 row-major, 8 MB
#define OFF_MROWS  ((1 << 16) + (12 << 20))   // bf16 mask rows, 512 KB

typedef float vf4 __attribute__((ext_vector_type(4)));
typedef float f32x2 __attribute__((ext_vector_type(2)));

__device__ __forceinline__ float bflo(unsigned u) { return __uint_as_float(u << 16); }
__device__ __forceinline__ float bfhi(unsigned u) { return __uint_as_float(u & 0xFFFF0000u); }
__device__ __forceinline__ unsigned short bf_rne(float f) {
    unsigned u = __float_as_uint(f);
    return (unsigned short)((u + 0x7FFFu + ((u >> 16) & 1u)) >> 16);
}
__device__ __forceinline__ unsigned pack2_rne(float a, float b) {
    return (unsigned)bf_rne(a) | ((unsigned)bf_rne(b) << 16);
}

// ---- fp8 e4m3 helpers: prefer HW cvt (OCP on gfx950); SW fallback kept
// format-consistent (encode+decode pair used together only).
#if __has_builtin(__builtin_amdgcn_cvt_pk_fp8_f32) && __has_builtin(__builtin_amdgcn_cvt_pk_f32_fp8)
#define FP8_HW 1
#else
#define FP8_HW 0
#endif

__device__ __forceinline__ unsigned char sw_f32_to_e4m3(float f) {
    unsigned u = __float_as_uint(f);
    unsigned s = (u >> 24) & 0x80u;
    float af = fabsf(f);
    if (af >= 448.f) return (unsigned char)(s | 0x7E);
    if (af < 0.015625f) {  // subnormal range: round(af * 512)
        int q = (int)(af * 512.f + 0.5f);
        return (unsigned char)(s | (unsigned)q);
    }
    unsigned lsb = (u >> 20) & 1u;
    u += 0x7FFFFu + lsb;
    int e = (int)(u >> 23) - 120;   // -127 + 7
    unsigned m = (u >> 20) & 7u;
    if (e >= 16) return (unsigned char)(s | 0x7E);
    return (unsigned char)(s | ((unsigned)e << 3) | m);
}
__device__ __forceinline__ float sw_e4m3_to_f32(unsigned b) {
    unsigned s = (b & 0x80u) << 24;
    unsigned e = (b >> 3) & 0xFu, m = b & 7u;
    if (e == 0) {
        float v = (float)m * 0.001953125f;
        return (b & 0x80u) ? -v : v;
    }
    return __uint_as_float(s | ((e + 120u) << 23) | (m << 20));
}

__device__ __forceinline__ unsigned enc_fp8x4(float x, float y, float z, float w) {
#if FP8_HW
    int r = 0;
    r = __builtin_amdgcn_cvt_pk_fp8_f32(x, y, r, false);
    r = __builtin_amdgcn_cvt_pk_fp8_f32(z, w, r, true);
    return (unsigned)r;
#else
    return (unsigned)sw_f32_to_e4m3(x) | ((unsigned)sw_f32_to_e4m3(y) << 8)
         | ((unsigned)sw_f32_to_e4m3(z) << 16) | ((unsigned)sw_f32_to_e4m3(w) << 24);
#endif
}

// dot over one 4-dim word pair: sum_i a_i*b_i*v_i
__device__ __forceinline__ float dot4_fp8(unsigned aw, unsigned bw, const float4 v) {
#if FP8_HW
    f32x2 al = __builtin_amdgcn_cvt_pk_f32_fp8((int)aw, false);
    f32x2 ah = __builtin_amdgcn_cvt_pk_f32_fp8((int)aw, true);
    f32x2 bl = __builtin_amdgcn_cvt_pk_f32_fp8((int)bw, false);
    f32x2 bh = __builtin_amdgcn_cvt_pk_f32_fp8((int)bw, true);
    return (al.x * bl.x) * v.x + (al.y * bl.y) * v.y
         + (ah.x * bh.x) * v.z + (ah.y * bh.y) * v.w;
#else
    return sw_e4m3_to_f32(aw & 255u) * sw_e4m3_to_f32(bw & 255u) * v.x
         + sw_e4m3_to_f32((aw >> 8) & 255u) * sw_e4m3_to_f32((bw >> 8) & 255u) * v.y
         + sw_e4m3_to_f32((aw >> 16) & 255u) * sw_e4m3_to_f32((bw >> 16) & 255u) * v.z
         + sw_e4m3_to_f32(aw >> 24) * sw_e4m3_to_f32(bw >> 24) * v.w;
#endif
}

// block 0: vc[d] = sum_j w1[d,j]*w2[j], vc[256] = b1.w2+b2  (wave-per-row, coalesced)
// block 1: counting-sort m by batch pointer
__global__ void setup_k(const float* __restrict__ w1, const float* __restrict__ b1,
                        const float* __restrict__ w2, const float* __restrict__ b2,
                        const int* __restrict__ bp,
                        float* __restrict__ vc, int* __restrict__ msorted,
                        int* __restrict__ bstart) {
    const int t = threadIdx.x;
    if (blockIdx.x == 0) {
        __shared__ float sw2[DD / 2];
        if (t < DD / 2) sw2[t] = w2[t];
        __syncthreads();
        const int lane = t & 63, w = t >> 6;
        for (int r = w; r < DD; r += 4) {
            float x = w1[r * (DD / 2) + lane] * sw2[lane]
                    + w1[r * (DD / 2) + 64 + lane] * sw2[64 + lane];
            x += __shfl_down(x, 32);
            x += __shfl_down(x, 16);
            x += __shfl_down(x, 8);
            x += __shfl_down(x, 4);
            x += __shfl_down(x, 2);
            x += __shfl_down(x, 1);
            if (lane == 0) vc[r] = x;
        }
        if (w == 0) {
            float x = b1[lane] * sw2[lane] + b1[64 + lane] * sw2[64 + lane];
            x += __shfl_down(x, 32);
            x += __shfl_down(x, 16);
            x += __shfl_down(x, 8);
            x += __shfl_down(x, 4);
            x += __shfl_down(x, 2);
            x += __shfl_down(x, 1);
            if (lane == 0) vc[DD] = x + b2[0];
        }
    } else {
        __shared__ int hist[BB];
        __shared__ int offs[BB + 1];
        if (t < BB) hist[t] = 0;
        __syncthreads();
        for (int m = t; m < MM; m += 256) atomicAdd(&hist[bp[m]], 1);
        __syncthreads();
        if (t == 0) {
            int acc = 0;
            for (int i = 0; i < BB; ++i) { offs[i] = acc; acc += hist[i]; }
            offs[BB] = acc;
        }
        __syncthreads();
        if (t < BB + 1) bstart[t] = offs[t];
        __syncthreads();
        for (int m = t; m < MM; m += 256) {
            int pos = atomicAdd(&offs[bp[m]], 1);
            msorted[pos] = m;
        }
    }
}

// Compact strided fp32 rows:
//  blocks [0, NROWS/4): type rows -> fslab (fp8 row-major, 256 B/row, for the
//                       edge gathers) + p2 (bf16 row-major, for lm staging)
//  blocks [NROWS/4, +MM/4): mask rows via lm_indices -> mrows (bf16 row-major)
__global__ __launch_bounds__(256) void compact(
        const float* __restrict__ tok, const int* __restrict__ lmi,
        unsigned* __restrict__ fslab,
        unsigned* __restrict__ p2, unsigned* __restrict__ mrows) {
    const int lane = threadIdx.x & 63;
    const int w    = threadIdx.x >> 6;
    if (blockIdx.x < NROWS / 4) {
        const int row = blockIdx.x * 4 + w;
        const float4 a = ((const float4*)tok)[(size_t)row * ROWF4 + lane];
        fslab[(size_t)row * 64 + lane] = enc_fp8x4(a.x, a.y, a.z, a.w);
        const size_t pi = (size_t)row * 128 + lane * 2;
        p2[pi]     = pack2_rne(a.x, a.y);
        p2[pi + 1] = pack2_rne(a.z, a.w);
    } else {
        const int m = (blockIdx.x - NROWS / 4) * 4 + w;
        const float4 a = ((const float4*)(tok + (size_t)lmi[m] * DD))[lane];
        mrows[(size_t)m * 128 + lane * 2]     = pack2_rne(a.x, a.y);
        mrows[(size_t)m * 128 + lane * 2 + 1] = pack2_rne(a.z, a.w);
    }
}

// Fused fp8 edge kernel: free-running grid, 256 edges/block. Row = 256 B fp8
// -> a full row is one dwordx4 per lane across 16 lanes; a wave handles 4
// edges per (scope,goal) load pair. 8 random 64-B segments per edge (vs 16
// for bf16) — attacks the measured request-rate floor directly.
__global__ __launch_bounds__(256) void edge_fp8(
        const unsigned* __restrict__ fslab,
        const int* __restrict__ edges, const float* __restrict__ vc,
        float* __restrict__ out) {
    const int t = threadIdx.x;
    const int lane = t & 63, w = t >> 6;
    const int l16 = lane & 15;     // 16-B chunk within the row
    const int g = lane >> 4;       // edge subgroup 0..3 within wave
    const int e0 = blockIdx.x * 256;

    __shared__ int sIdx[2][256];
    __shared__ float accs[256];
    const int e = e0 + t;
    const bool val = e < NEDGE;
    sIdx[0][t] = val ? __builtin_nontemporal_load(edges + e) : 0;
    sIdx[1][t] = val ? __builtin_nontemporal_load(edges + NEDGE + e) : 0;

    // per-lane v weights: dims [l16*16, l16*16+16)
    const float4 v0 = ((const float4*)vc)[l16 * 4 + 0];
    const float4 v1 = ((const float4*)vc)[l16 * 4 + 1];
    const float4 v2 = ((const float4*)vc)[l16 * 4 + 2];
    const float4 v3 = ((const float4*)vc)[l16 * 4 + 3];
    __syncthreads();

    #pragma unroll 4
    for (int it = 0; it < 16; ++it) {
        const int slot = w * 64 + it * 4 + g;
        const int sc = sIdx[0][slot];
        const int gl = sIdx[1][slot];
        const uint4 A = *(const uint4*)(fslab + (size_t)sc * 64 + l16 * 4);
        const uint4 B = *(const uint4*)(fslab + (size_t)gl * 64 + l16 * 4);
        float s = dot4_fp8(A.x, B.x, v0) + dot4_fp8(A.y, B.y, v1)
                + dot4_fp8(A.z, B.z, v2) + dot4_fp8(A.w, B.w, v3);
        s += __shfl_down(s, 8, 16);
        s += __shfl_down(s, 4, 16);
        s += __shfl_down(s, 2, 16);
        s += __shfl_down(s, 1, 16);
        if (l16 == 0) accs[slot] = s;
    }
    __syncthreads();
    const float c = vc[DD];
    if (val) __builtin_nontemporal_store(accs[t] + c, out + e);
}

// Per-batch grouped lm GEMM with masked-column skip; A and B staged from
// dense bf16 tables (proven round-0/3 version).
__global__ __launch_bounds__(256) void lm_gemm(
        const unsigned* __restrict__ p2,
        const unsigned* __restrict__ mrows,
        const int* __restrict__ msorted,
        const int* __restrict__ bstart,
        const int* __restrict__ tpm,
        float* __restrict__ out) {
    const int b  = blockIdx.x;
    const int st = blockIdx.y;   // 64-wide s tile
    const int ch = blockIdx.z;   // mask chunk
    const int s0 = bstart[b], s1 = bstart[b + 1];
    const int base = s0 + ch * 32;
    if (base >= s1) return;
    const int nm = min(32, s1 - base);
    const int t = threadIdx.x;

    __shared__ unsigned lmaskU[32 * 132];
    __shared__ unsigned srowU[32 * 132];
    __shared__ int mids[32];
    __shared__ int sact[64];
    __shared__ int snact;

    if (t < 32) mids[t] = msorted[base + min(t, nm - 1)];
    if (t >= 64 && t < 128) {  // wave 1: ballot-compact active columns
        int lt = t - 64;
        bool act = tpm[b * SS + st * 64 + lt] != 0;
        unsigned long long mk = __ballot(act);
        if (act) sact[__popcll(mk & ((1ull << lt) - 1))] = lt;
        if (lt == 0) snact = (int)__popcll(mk);
    }
    __syncthreads();

    for (int f = t; f < nm * 32; f += 256) {
        int r = f >> 5, q = f & 31;
        *(uint4*)&lmaskU[r * 132 + q * 4] = ((const uint4*)mrows)[(size_t)mids[r] * 32 + q];
    }
    for (int f = t; f < nm * 64; f += 256) {
        int i = f >> 6, c = f & 63;
        if (!tpm[b * SS + st * 64 + c])
            out[(size_t)mids[i] * SS + st * 64 + c] = NEG_INF;
    }
    __syncthreads();

    const int nact = snact;
    const int i2 = t & 15, sg = t >> 4;

    for (int g = 0; g * 32 < nact; ++g) {
        if (g) __syncthreads();
        const int nv = min(32, nact - g * 32);
        for (int f = t; f < nv * 32; f += 256) {
            int r = f >> 5, q = f & 31;
            size_t row = (size_t)b * SS + st * 64 + sact[g * 32 + r];
            *(uint4*)&srowU[r * 132 + q * 4] = ((const uint4*)p2)[row * 32 + q];
        }
        __syncthreads();

        float a00 = 0.f, a01 = 0.f, a10 = 0.f, a11 = 0.f;
        #pragma unroll 4
        for (int stp = 0; stp < 32; ++stp) {
            const uint4 A0 = *(const uint4*)&lmaskU[i2 * 132 + stp * 4];
            const uint4 A1 = *(const uint4*)&lmaskU[(i2 + 16) * 132 + stp * 4];
            const uint4 B0 = *(const uint4*)&srowU[sg * 132 + stp * 4];
            const uint4 B1 = *(const uint4*)&srowU[(sg + 16) * 132 + stp * 4];
            float a0[8], a1[8], b0[8], b1[8];
            a0[0] = bflo(A0.x); a0[1] = bfhi(A0.x); a0[2] = bflo(A0.y); a0[3] = bfhi(A0.y);
            a0[4] = bflo(A0.z); a0[5] = bfhi(A0.z); a0[6] = bflo(A0.w); a0[7] = bfhi(A0.w);
            a1[0] = bflo(A1.x); a1[1] = bfhi(A1.x); a1[2] = bflo(A1.y); a1[3] = bfhi(A1.y);
            a1[4] = bflo(A1.z); a1[5] = bfhi(A1.z); a1[6] = bflo(A1.w); a1[7] = bfhi(A1.w);
            b0[0] = bflo(B0.x); b0[1] = bfhi(B0.x); b0[2] = bflo(B0.y); b0[3] = bfhi(B0.y);
            b0[4] = bflo(B0.z); b0[5] = bfhi(B0.z); b0[6] = bflo(B0.w); b0[7] = bfhi(B0.w);
            b1[0] = bflo(B1.x); b1[1] = bfhi(B1.x); b1[2] = bflo(B1.y); b1[3] = bfhi(B1.y);
            b1[4] = bflo(B1.z); b1[5] = bfhi(B1.z); b1[6] = bflo(B1.w); b1[7] = bfhi(B1.w);
            #pragma unroll
            for (int jj = 0; jj < 8; ++jj) {
                a00 = fmaf(a0[jj], b0[jj], a00);
                a01 = fmaf(a0[jj], b1[jj], a01);
                a10 = fmaf(a1[jj], b0[jj], a10);
                a11 = fmaf(a1[jj], b1[jj], a11);
            }
        }

        const int iA = g * 32 + sg, iB = iA + 16;
        if (i2 < nm) {
            size_t ob = (size_t)mids[i2] * SS + st * 64;
            if (iA < nact) out[ob + sact[iA]] = a00;
            if (iB < nact) out[ob + sact[iB]] = a01;
        }
        if (i2 + 16 < nm) {
            size_t ob = (size_t)mids[i2 + 16] * SS + st * 64;
            if (iA < nact) out[ob + sact[iA]] = a10;
            if (iB < nact) out[ob + sact[iB]] = a11;
        }
    }
}

extern "C" void kernel_launch(void* const* d_in, const int* in_sizes, int n_in,
                              void* d_out, int out_size, void* d_ws, size_t ws_size,
                              hipStream_t stream) {
    const float* tok = (const float*)d_in[0];
    const float* w1  = (const float*)d_in[1];
    const float* b1  = (const float*)d_in[2];
    const float* w2  = (const float*)d_in[3];
    const float* b2  = (const float*)d_in[4];
    const int* edges = (const int*)d_in[5];
    const int* lmi   = (const int*)d_in[6];
    const int* bp    = (const int*)d_in[7];
    const int* tpm   = (const int*)d_in[8];

    float* out_lemmas = (float*)d_out;
    float* out_lm     = (float*)d_out + NEDGE;

    char* ws = (char*)d_ws;
    float* vc        = (float*)(ws + OFF_VC);
    int* msorted     = (int*)(ws + OFF_MSORT);
    int* bstart      = (int*)(ws + OFF_BSTART);
    unsigned* fslab  = (unsigned*)(ws + OFF_FSLAB);
    unsigned* p2     = (unsigned*)(ws + OFF_P2);
    unsigned* mrows  = (unsigned*)(ws + OFF_MROWS);

    setup_k<<<2, 256, 0, stream>>>(w1, b1, w2, b2, bp, vc, msorted, bstart);
    compact<<<NROWS / 4 + MM / 4, 256, 0, stream>>>(tok, lmi, fslab, p2, mrows);
    edge_fp8<<<(NEDGE + 255) / 256, 256, 0, stream>>>(fslab, edges, vc, out_lemmas);
    lm_gemm<<<dim3(BB, 4, 8), 256, 0, stream>>>(p2, mrows, msorted, bstart, tpm, out_lm);
}

// Round 6
// 247.360 us; speedup vs baseline: 1.3921x; 1.0569x over previous
//
#include <hip/hip_runtime.h>

#define DD 256        // D
#define SS 256        // S
#define BB 64         // B
#define NEDGE 500000  // E
#define MM 2048       // M
#define NEG_INF -10000000000.0f
#define ROWF4 512     // float4 stride between consecutive (b,s) type rows in token_reprs
#define NROWS (BB * SS)  // 16384

// workspace byte offsets (ws is 512 MB per harness poison fills)
#define OFF_VC     0
#define OFF_MSORT  4096
#define OFF_BSTART (4096 + MM * 4)
#define OFF_FSLAB  (1 << 16)                  // fp8 table, 16384 x 256 B = 4 MB
#define OFF_P2     ((1 << 16) + (4 << 20))    // bf16 row-major, 8 MB
#define OFF_MROWS  ((1 << 16) + (12 << 20))   // bf16 mask rows, 512 KB

typedef float vf4 __attribute__((ext_vector_type(4)));
typedef float f32x2 __attribute__((ext_vector_type(2)));
typedef float f32x4 __attribute__((ext_vector_type(4)));
typedef short bf16x8 __attribute__((ext_vector_type(8)));

__device__ __forceinline__ float bflo(unsigned u) { return __uint_as_float(u << 16); }
__device__ __forceinline__ float bfhi(unsigned u) { return __uint_as_float(u & 0xFFFF0000u); }
__device__ __forceinline__ unsigned short bf_rne(float f) {
    unsigned u = __float_as_uint(f);
    return (unsigned short)((u + 0x7FFFu + ((u >> 16) & 1u)) >> 16);
}
__device__ __forceinline__ unsigned pack2_rne(float a, float b) {
    return (unsigned)bf_rne(a) | ((unsigned)bf_rne(b) << 16);
}

// ---- fp8 e4m3 helpers: prefer HW cvt (OCP on gfx950); SW fallback kept
// format-consistent (encode+decode pair used together only).
#if __has_builtin(__builtin_amdgcn_cvt_pk_fp8_f32) && __has_builtin(__builtin_amdgcn_cvt_pk_f32_fp8)
#define FP8_HW 1
#else
#define FP8_HW 0
#endif

__device__ __forceinline__ unsigned char sw_f32_to_e4m3(float f) {
    unsigned u = __float_as_uint(f);
    unsigned s = (u >> 24) & 0x80u;
    float af = fabsf(f);
    if (af >= 448.f) return (unsigned char)(s | 0x7E);
    if (af < 0.015625f) {
        int q = (int)(af * 512.f + 0.5f);
        return (unsigned char)(s | (unsigned)q);
    }
    unsigned lsb = (u >> 20) & 1u;
    u += 0x7FFFFu + lsb;
    int e = (int)(u >> 23) - 120;
    unsigned m = (u >> 20) & 7u;
    if (e >= 16) return (unsigned char)(s | 0x7E);
    return (unsigned char)(s | ((unsigned)e << 3) | m);
}
__device__ __forceinline__ float sw_e4m3_to_f32(unsigned b) {
    unsigned s = (b & 0x80u) << 24;
    unsigned e = (b >> 3) & 0xFu, m = b & 7u;
    if (e == 0) {
        float v = (float)m * 0.001953125f;
        return (b & 0x80u) ? -v : v;
    }
    return __uint_as_float(s | ((e + 120u) << 23) | (m << 20));
}

__device__ __forceinline__ unsigned enc_fp8x4(float x, float y, float z, float w) {
#if FP8_HW
    int r = 0;
    r = __builtin_amdgcn_cvt_pk_fp8_f32(x, y, r, false);
    r = __builtin_amdgcn_cvt_pk_fp8_f32(z, w, r, true);
    return (unsigned)r;
#else
    return (unsigned)sw_f32_to_e4m3(x) | ((unsigned)sw_f32_to_e4m3(y) << 8)
         | ((unsigned)sw_f32_to_e4m3(z) << 16) | ((unsigned)sw_f32_to_e4m3(w) << 24);
#endif
}

__device__ __forceinline__ float dot4_fp8(unsigned aw, unsigned bw, const float4 v) {
#if FP8_HW
    f32x2 al = __builtin_amdgcn_cvt_pk_f32_fp8((int)aw, false);
    f32x2 ah = __builtin_amdgcn_cvt_pk_f32_fp8((int)aw, true);
    f32x2 bl = __builtin_amdgcn_cvt_pk_f32_fp8((int)bw, false);
    f32x2 bh = __builtin_amdgcn_cvt_pk_f32_fp8((int)bw, true);
    return (al.x * bl.x) * v.x + (al.y * bl.y) * v.y
         + (ah.x * bh.x) * v.z + (ah.y * bh.y) * v.w;
#else
    return sw_e4m3_to_f32(aw & 255u) * sw_e4m3_to_f32(bw & 255u) * v.x
         + sw_e4m3_to_f32((aw >> 8) & 255u) * sw_e4m3_to_f32((bw >> 8) & 255u) * v.y
         + sw_e4m3_to_f32((aw >> 16) & 255u) * sw_e4m3_to_f32((bw >> 16) & 255u) * v.z
         + sw_e4m3_to_f32(aw >> 24) * sw_e4m3_to_f32(bw >> 24) * v.w;
#endif
}

// Fused prep kernel (compact + setup merged; setup's 2 blocks ride along the
// compact grid instead of serializing as their own launch):
//  blocks [0, NROWS/4): type rows -> fslab (fp8 row-major) + p2 (bf16 row-major)
//  blocks [NROWS/4, +MM/4): mask rows via lm_indices -> mrows (bf16 row-major)
//  block NROWS/4+MM/4:   vc[d] = sum_j w1[d,j]*w2[j], vc[256] = b1.w2+b2
//  block NROWS/4+MM/4+1: counting-sort m by batch pointer
__global__ __launch_bounds__(256) void prep(
        const float* __restrict__ tok, const int* __restrict__ lmi,
        const float* __restrict__ w1, const float* __restrict__ b1,
        const float* __restrict__ w2, const float* __restrict__ b2,
        const int* __restrict__ bp,
        unsigned* __restrict__ fslab,
        unsigned* __restrict__ p2, unsigned* __restrict__ mrows,
        float* __restrict__ vc, int* __restrict__ msorted,
        int* __restrict__ bstart) {
    const int t = threadIdx.x;
    const int lane = t & 63;
    const int w    = t >> 6;
    if (blockIdx.x < NROWS / 4) {
        const int row = blockIdx.x * 4 + w;
        const float4 a = ((const float4*)tok)[(size_t)row * ROWF4 + lane];
        fslab[(size_t)row * 64 + lane] = enc_fp8x4(a.x, a.y, a.z, a.w);
        const size_t pi = (size_t)row * 128 + lane * 2;
        p2[pi]     = pack2_rne(a.x, a.y);
        p2[pi + 1] = pack2_rne(a.z, a.w);
    } else if (blockIdx.x < NROWS / 4 + MM / 4) {
        const int m = (blockIdx.x - NROWS / 4) * 4 + w;
        const float4 a = ((const float4*)(tok + (size_t)lmi[m] * DD))[lane];
        mrows[(size_t)m * 128 + lane * 2]     = pack2_rne(a.x, a.y);
        mrows[(size_t)m * 128 + lane * 2 + 1] = pack2_rne(a.z, a.w);
    } else if (blockIdx.x == NROWS / 4 + MM / 4) {
        __shared__ float sw2[DD / 2];
        if (t < DD / 2) sw2[t] = w2[t];
        __syncthreads();
        for (int r = w; r < DD; r += 4) {
            float x = w1[r * (DD / 2) + lane] * sw2[lane]
                    + w1[r * (DD / 2) + 64 + lane] * sw2[64 + lane];
            x += __shfl_down(x, 32);
            x += __shfl_down(x, 16);
            x += __shfl_down(x, 8);
            x += __shfl_down(x, 4);
            x += __shfl_down(x, 2);
            x += __shfl_down(x, 1);
            if (lane == 0) vc[r] = x;
        }
        if (w == 0) {
            float x = b1[lane] * sw2[lane] + b1[64 + lane] * sw2[64 + lane];
            x += __shfl_down(x, 32);
            x += __shfl_down(x, 16);
            x += __shfl_down(x, 8);
            x += __shfl_down(x, 4);
            x += __shfl_down(x, 2);
            x += __shfl_down(x, 1);
            if (lane == 0) vc[DD] = x + b2[0];
        }
    } else {
        __shared__ int hist[BB];
        __shared__ int offs[BB + 1];
        if (t < BB) hist[t] = 0;
        __syncthreads();
        for (int m = t; m < MM; m += 256) atomicAdd(&hist[bp[m]], 1);
        __syncthreads();
        if (t == 0) {
            int acc = 0;
            for (int i = 0; i < BB; ++i) { offs[i] = acc; acc += hist[i]; }
            offs[BB] = acc;
        }
        __syncthreads();
        if (t < BB + 1) bstart[t] = offs[t];
        __syncthreads();
        for (int m = t; m < MM; m += 256) {
            int pos = atomicAdd(&offs[bp[m]], 1);
            msorted[pos] = m;
        }
    }
}

// Fused fp8 edge kernel (unchanged from round 5): 256 edges/block, 16 lanes
// per edge, 8 random 64-B segments/edge.
__global__ __launch_bounds__(256) void edge_fp8(
        const unsigned* __restrict__ fslab,
        const int* __restrict__ edges, const float* __restrict__ vc,
        float* __restrict__ out) {
    const int t = threadIdx.x;
    const int lane = t & 63, w = t >> 6;
    const int l16 = lane & 15;
    const int g = lane >> 4;
    const int e0 = blockIdx.x * 256;

    __shared__ int sIdx[2][256];
    __shared__ float accs[256];
    const int e = e0 + t;
    const bool val = e < NEDGE;
    sIdx[0][t] = val ? __builtin_nontemporal_load(edges + e) : 0;
    sIdx[1][t] = val ? __builtin_nontemporal_load(edges + NEDGE + e) : 0;

    const float4 v0 = ((const float4*)vc)[l16 * 4 + 0];
    const float4 v1 = ((const float4*)vc)[l16 * 4 + 1];
    const float4 v2 = ((const float4*)vc)[l16 * 4 + 2];
    const float4 v3 = ((const float4*)vc)[l16 * 4 + 3];
    __syncthreads();

    #pragma unroll 4
    for (int it = 0; it < 16; ++it) {
        const int slot = w * 64 + it * 4 + g;
        const int sc = sIdx[0][slot];
        const int gl = sIdx[1][slot];
        const uint4 A = *(const uint4*)(fslab + (size_t)sc * 64 + l16 * 4);
        const uint4 B = *(const uint4*)(fslab + (size_t)gl * 64 + l16 * 4);
        float s = dot4_fp8(A.x, B.x, v0) + dot4_fp8(A.y, B.y, v1)
                + dot4_fp8(A.z, B.z, v2) + dot4_fp8(A.w, B.w, v3);
        s += __shfl_down(s, 8, 16);
        s += __shfl_down(s, 4, 16);
        s += __shfl_down(s, 2, 16);
        s += __shfl_down(s, 1, 16);
        if (l16 == 0) accs[slot] = s;
    }
    __syncthreads();
    const float c = vc[DD];
    if (val) __builtin_nontemporal_store(accs[t] + c, out + e);
}

// Per-batch grouped lm GEMM, MFMA version. Staging/masking structure is the
// proven round-0 one; the scalar bf16-unpack+FMA inner loop is replaced by
// mfma_f32_16x16x32_bf16. Per g-group: 2x2 C-tiles (32 masks x 32 active s),
// one tile per wave, 8 K-steps of 32 dims.
__global__ __launch_bounds__(256) void lm_gemm(
        const unsigned* __restrict__ p2,
        const unsigned* __restrict__ mrows,
        const int* __restrict__ msorted,
        const int* __restrict__ bstart,
        const int* __restrict__ tpm,
        float* __restrict__ out) {
    const int b  = blockIdx.x;
    const int st = blockIdx.y;   // 64-wide s tile
    const int ch = blockIdx.z;   // mask chunk
    const int s0 = bstart[b], s1 = bstart[b + 1];
    const int base = s0 + ch * 32;
    if (base >= s1) return;
    const int nm = min(32, s1 - base);
    const int t = threadIdx.x;

    __shared__ __align__(16) unsigned lmaskU[32 * 132];
    __shared__ __align__(16) unsigned srowU[32 * 132];
    __shared__ int mids[32];
    __shared__ int sact[64];
    __shared__ int snact;

    if (t < 32) mids[t] = msorted[base + min(t, nm - 1)];
    if (t >= 64 && t < 128) {  // wave 1: ballot-compact active columns
        int lt = t - 64;
        bool act = tpm[b * SS + st * 64 + lt] != 0;
        unsigned long long mk = __ballot(act);
        if (act) sact[__popcll(mk & ((1ull << lt) - 1))] = lt;
        if (lt == 0) snact = (int)__popcll(mk);
    }
    __syncthreads();

    for (int f = t; f < nm * 32; f += 256) {
        int r = f >> 5, q = f & 31;
        *(uint4*)&lmaskU[r * 132 + q * 4] = ((const uint4*)mrows)[(size_t)mids[r] * 32 + q];
    }
    for (int f = t; f < nm * 64; f += 256) {
        int i = f >> 6, c = f & 63;
        if (!tpm[b * SS + st * 64 + c])
            out[(size_t)mids[i] * SS + st * 64 + c] = NEG_INF;
    }
    __syncthreads();

    const int nact = snact;
    const int lane = t & 63;
    const int wv = t >> 6;        // 4 waves
    const int rt = wv >> 1;       // row-tile (mask half) 0..1
    const int ct = wv & 1;        // col-tile within g 0..1
    const int fr = lane & 15;     // fragment row/col
    const int fq = lane >> 4;     // k-group 0..3

    for (int g = 0; g * 32 < nact; ++g) {
        if (g) __syncthreads();
        const int nv = min(32, nact - g * 32);
        for (int f = t; f < nv * 32; f += 256) {
            int r = f >> 5, q = f & 31;
            size_t row = (size_t)b * SS + st * 64 + sact[g * 32 + r];
            *(uint4*)&srowU[r * 132 + q * 4] = ((const uint4*)p2)[row * 32 + q];
        }
        __syncthreads();

        // A: lmask row rt*16+fr, dims stp*32 + fq*8 (8 bf16 = 4 uints)
        // B: srow  row ct*16+fr, same dim slice (dot over d => same addressing)
        f32x4 acc = {0.f, 0.f, 0.f, 0.f};
        #pragma unroll
        for (int stp = 0; stp < 8; ++stp) {
            bf16x8 a = *(const bf16x8*)&lmaskU[(rt * 16 + fr) * 132 + stp * 16 + fq * 4];
            bf16x8 bfr = *(const bf16x8*)&srowU[(ct * 16 + fr) * 132 + stp * 16 + fq * 4];
            acc = __builtin_amdgcn_mfma_f32_16x16x32_bf16(a, bfr, acc, 0, 0, 0);
        }

        // D: col = lane&15 (s within tile), row = (lane>>4)*4 + r (mask)
        const int jg = g * 32 + ct * 16 + fr;
        if (jg < nact) {
            const int sj = sact[jg];
            #pragma unroll
            for (int r = 0; r < 4; ++r) {
                const int mi = rt * 16 + fq * 4 + r;
                if (mi < nm) out[(size_t)mids[mi] * SS + st * 64 + sj] = acc[r];
            }
        }
    }
}

extern "C" void kernel_launch(void* const* d_in, const int* in_sizes, int n_in,
                              void* d_out, int out_size, void* d_ws, size_t ws_size,
                              hipStream_t stream) {
    const float* tok = (const float*)d_in[0];
    const float* w1  = (const float*)d_in[1];
    const float* b1  = (const float*)d_in[2];
    const float* w2  = (const float*)d_in[3];
    const float* b2  = (const float*)d_in[4];
    const int* edges = (const int*)d_in[5];
    const int* lmi   = (const int*)d_in[6];
    const int* bp    = (const int*)d_in[7];
    const int* tpm   = (const int*)d_in[8];

    float* out_lemmas = (float*)d_out;
    float* out_lm     = (float*)d_out + NEDGE;

    char* ws = (char*)d_ws;
    float* vc        = (float*)(ws + OFF_VC);
    int* msorted     = (int*)(ws + OFF_MSORT);
    int* bstart      = (int*)(ws + OFF_BSTART);
    unsigned* fslab  = (unsigned*)(ws + OFF_FSLAB);
    unsigned* p2     = (unsigned*)(ws + OFF_P2);
    unsigned* mrows  = (unsigned*)(ws + OFF_MROWS);

    prep<<<NROWS / 4 + MM / 4 + 2, 256, 0, stream>>>(
        tok, lmi, w1, b1, w2, b2, bp, fslab, p2, mrows, vc, msorted, bstart);
    edge_fp8<<<(NEDGE + 255) / 256, 256, 0, stream>>>(fslab, edges, vc, out_lemmas);
    lm_gemm<<<dim3(BB, 4, 8), 256, 0, stream>>>(p2, mrows, msorted, bstart, tpm, out_lm);
}